// Round 8
// baseline (230.896 us; speedup 1.0000x reference)
//
#include <hip/hip_runtime.h>

typedef __attribute__((ext_vector_type(8))) short s8v;          // 8 x bf16 (raw)
typedef __attribute__((ext_vector_type(4))) float f4v;
typedef __attribute__((ext_vector_type(4))) unsigned short u4v;
typedef __attribute__((ext_vector_type(2))) unsigned int u2v;
typedef __attribute__((ext_vector_type(4))) float fl4;

#define MFMA __builtin_amdgcn_mfma_f32_16x16x32_bf16
#define LOG2E 1.44269504088896340736f
#define QSCALE (0.125f * LOG2E)   // fold 1/sqrt(DK) and log2(e) into q

// round-half-up bf16 (0.5 ulp, fine for our budget)
__device__ __forceinline__ unsigned short f2bf(float f) {
  return (unsigned short)((__float_as_uint(f) + 0x8000u) >> 16);
}
// pack two floats -> two bf16 in one dword (low = a, high = b)
__device__ __forceinline__ unsigned int pack_bf(float a, float b) {
  return __builtin_amdgcn_perm(__float_as_uint(b) + 0x8000u,
                               __float_as_uint(a) + 0x8000u, 0x07060302u);
}
__device__ __forceinline__ float bf2f(unsigned short u) {
  return __uint_as_float(((unsigned int)u) << 16);
}

__device__ __forceinline__ void gload16(const void* g, void* l) {
  __builtin_amdgcn_global_load_lds(
      (const __attribute__((address_space(1))) unsigned int*)g,
      (__attribute__((address_space(3))) unsigned int*)l,
      16, 0, 0);
}

// ---- 64x64 bf16 tile staging, XOR-chunk swizzle (LDS chunk (row,cl) holds
// global chunk (row, cl^(row&7))); frag64 applies the same XOR on read.
__device__ __forceinline__ void stage64(unsigned short* lds,
                                        const unsigned short* src,
                                        int src_ld, int tid) {
  const int w = tid >> 6, l = tid & 63;
#pragma unroll
  for (int c = 0; c < 2; ++c) {
    int idx = (c * 4 + w) * 64 + l;
    int row = idx >> 3, cl = idx & 7;
    gload16(src + row * src_ld + ((cl ^ (row & 7)) << 3),
            lds + (c * 4 + w) * 512);
  }
}
// ---- 128x64 bf16 tile staging (for 128^2 GEMM)
__device__ __forceinline__ void stage128(unsigned short* lds,
                                         const unsigned short* src,
                                         int src_ld, int tid) {
  const int w = tid >> 6, l = tid & 63;
#pragma unroll
  for (int c = 0; c < 4; ++c) {
    int id = c * 256 + w * 64 + l;
    int row = id >> 3, cl = id & 7;
    gload16(src + row * src_ld + ((cl ^ (row & 7)) << 3),
            lds + (c * 256 + w * 64) * 8);
  }
}
__device__ __forceinline__ s8v frag64(const unsigned short* lds, int row, int chunk) {
  return *(const s8v*)(lds + row * 64 + ((chunk ^ (row & 7)) << 3));
}

// ---------------- converts (merged: wqkv rows 0..767, wo 768..1023, rel 1024..1055) ----
__global__ void cvt_all(const float* __restrict__ wq, const float* __restrict__ wk,
                        const float* __restrict__ wv, const float* __restrict__ wo,
                        const float* __restrict__ relh, const float* __restrict__ relw,
                        unsigned short* __restrict__ Wqkv, unsigned short* __restrict__ Wob,
                        unsigned short* __restrict__ Rel) {
  const int bid = blockIdx.x, tid = threadIdx.x;
  if (bid < 768) {
    int i = bid * 256 + tid;                       // 1536*128
    int orow = i >> 7, c4 = (i & 127) * 4;
    int p = orow >> 9, oc = orow & 511;
    int h = oc >> 6, d = oc & 63;
    const float* w = (p == 0) ? wq : (p == 1) ? wk : wv;
    fl4 v = *(const fl4*)(w + (d * 8 + h) * 512 + c4);
    u4v o;
    o[0] = f2bf(v[0]); o[1] = f2bf(v[1]); o[2] = f2bf(v[2]); o[3] = f2bf(v[3]);
    *(u4v*)(Wqkv + orow * 512 + c4) = o;
  } else if (bid < 1024) {
    int i = (bid - 768) * 256 + tid;               // 65536 float4s
    fl4 v = ((const fl4*)wo)[i];
    u4v o;
    o[0] = f2bf(v[0]); o[1] = f2bf(v[1]); o[2] = f2bf(v[2]); o[3] = f2bf(v[3]);
    ((u4v*)Wob)[i] = o;
  } else {
    int i = (bid - 1024) * 256 + tid;              // [2][64][64], row 63 zeroed
    int t = i >> 12, r = (i >> 6) & 63, d = i & 63;
    const float* s = t ? relw : relh;
    Rel[i] = (r < 63) ? f2bf(s[r * 64 + d]) : (unsigned short)0;
  }
}

// x [B][C][N] f32 -> Xt [B][N][C] bf16
__global__ void xpose(const float* __restrict__ x, unsigned short* __restrict__ Xt) {
  __shared__ float tls[32][33];
  const int c0 = blockIdx.x * 32, n0 = blockIdx.y * 32, b = blockIdx.z;
  const int tid = threadIdx.x;
  const int rr = tid >> 3, cc4 = (tid & 7) * 4;
  fl4 v = *(const fl4*)(x + (b * 512 + c0 + rr) * 1024 + n0 + cc4);
#pragma unroll
  for (int i = 0; i < 4; ++i) tls[rr][cc4 + i] = v[i];
  __syncthreads();
  u4v o;
#pragma unroll
  for (int i = 0; i < 4; ++i) o[i] = f2bf(tls[cc4 + i][rr]);
  *(u4v*)(Xt + (b * 1024 + n0 + rr) * 512 + c0 + cc4) = o;
}

// ---------------- QKV projection, 128x128 tile ----------------
// 1-D grid, XCD-swizzled: cls=bid%8 keys the (n,b) B-panel class (n_idx=cls);
// within an XCD, same-(n,b) panels are consecutive across m (12x L2 reuse).
__global__ __launch_bounds__(256, 2)
void qkv_gemm(const unsigned short* __restrict__ W,
              const unsigned short* __restrict__ Xt,
              unsigned short* __restrict__ qb,
              unsigned short* __restrict__ kb,
              unsigned short* __restrict__ vtb) {
  __shared__ __align__(16) unsigned short Al[8192];
  __shared__ __align__(16) unsigned short Bl[8192];
  const int tid = threadIdx.x, w = tid >> 6, l = tid & 63;
  const int l15 = l & 15, lg = l >> 4;
  const int wr = w >> 1, wc = w & 1;
  const int bid = blockIdx.x;
  const int cls = bid & 7, idx = bid >> 3;     // 1536 blocks: cls=XCD class
  const int n0 = cls * 128;
  const int m0 = (idx % 12) * 128;
  const int b  = idx / 12;
  f4v acc[4][4] = {};
  const unsigned short* As = W + m0 * 512;
  const unsigned short* Bs = Xt + (b * 1024 + n0) * 512;
  for (int k0 = 0; k0 < 512; k0 += 64) {
    stage128(Al, As + k0, 512, tid);
    stage128(Bl, Bs + k0, 512, tid);
    __syncthreads();
#pragma unroll
    for (int kk = 0; kk < 2; ++kk) {
      s8v a[4], bb[4];
#pragma unroll
      for (int i = 0; i < 4; ++i) a[i] = frag64(Al + wr * 4096, i * 16 + l15, kk * 4 + lg);
#pragma unroll
      for (int j = 0; j < 4; ++j) bb[j] = frag64(Bl + wc * 4096, j * 16 + l15, kk * 4 + lg);
#pragma unroll
      for (int i = 0; i < 4; ++i)
#pragma unroll
        for (int j = 0; j < 4; ++j)
          acc[i][j] = MFMA(a[i], bb[j], acc[i][j], 0, 0, 0);
    }
    __syncthreads();
  }
  const int p = m0 >> 9;
  const float sc = (p == 0) ? QSCALE : 1.0f;
#pragma unroll
  for (int i = 0; i < 4; ++i) {
    int o = m0 + wr * 64 + i * 16 + lg * 4;
    int oc = o & 511, hh = oc >> 6, dd = oc & 63;
#pragma unroll
    for (int j = 0; j < 4; ++j) {
      int n = n0 + wc * 64 + j * 16 + l15;
      if (p < 2) {
        u2v pk;
        pk[0] = pack_bf(acc[i][j][0] * sc, acc[i][j][1] * sc);
        pk[1] = pack_bf(acc[i][j][2] * sc, acc[i][j][3] * sc);
        unsigned short* dst = (p == 0 ? qb : kb) + (((b * 8 + hh) * 1024 + n) * 64 + dd);
        *(u2v*)dst = pk;
      } else {
#pragma unroll
        for (int r = 0; r < 4; ++r)
          vtb[((b * 8 + hh) * 64 + dd + r) * 1024 + n] = f2bf(acc[i][j][r]);
      }
    }
  }
}

// ---------------- fused attention: prefetch double-buffer + XCD swizzle ----------------
// 1-D grid 2048: cls=bid%8 -> XCD class = bh%8; the 16 q-blocks of one head are
// consecutive within an XCD -> that head's K/V (256KB) stays L2-resident.
// Per tile: issue stage(t+1) BEFORE compute(t); single __syncthreads per tile
// (its vmcnt(0) drain lands after compute -> stage latency hidden).
__global__ __launch_bounds__(256, 4)
void attn_kernel(const unsigned short* __restrict__ qbuf,
                 const unsigned short* __restrict__ kbuf,
                 const unsigned short* __restrict__ vtbuf,
                 const unsigned short* __restrict__ relb,
                 unsigned short* __restrict__ AO) {
  __shared__ __align__(16) unsigned short SH[25344];
  unsigned short* K0  = SH;            // [64][64] xor-chunked  (4096 ea)
  unsigned short* V0  = SH + 4096;
  unsigned short* K1  = SH + 8192;
  unsigned short* V1  = SH + 12288;
  unsigned short* lhb = SH + 16384;    // [64][68] bf16 (lw scratch then lh; rows wave-private)
  unsigned short* PwB = SH + 20736;    // 4 x [16][72] bf16

  const int tid = threadIdx.x, w = tid >> 6, l = tid & 63;
  const int l15 = l & 15, lg = l >> 4;
  const int bid = blockIdx.x;
  const int cls = bid & 7, idx = bid >> 3;
  const int q0 = (idx & 15) * 64;
  const int bh = cls + 8 * (idx >> 4);
  const unsigned short* qh = qbuf + bh * 65536;
  const unsigned short* kh = kbuf + bh * 65536;
  const unsigned short* vh = vtbuf + bh * 65536;
  const int qloc = w * 16 + l15;
  const int qrow = q0 + qloc;
  const int x = qrow >> 5, y = qrow & 31;

  // issue tile-0 staging first; table work below hides its latency
  stage64(K0, kh, 64, tid);
  stage64(V0, vh, 1024, tid);

  // Q B-frags (own q row over d), q pre-scaled by log2e/8
  s8v bq[2];
#pragma unroll
  for (int kk = 0; kk < 2; ++kk)
    bq[kk] = *(const s8v*)(qh + qrow * 64 + kk * 32 + lg * 8);

  // lw table first (into lhb), read lw regs, then lh table (overwrites).
  // All rows wave-private -> DS in-order per wave, no barriers needed.
#pragma unroll
  for (int ct = 0; ct < 4; ++ct) {
    f4v c = {0.f, 0.f, 0.f, 0.f};
#pragma unroll
    for (int kk = 0; kk < 2; ++kk) {
      s8v a = *(const s8v*)(relb + 4096 + (ct * 16 + l15) * 64 + kk * 32 + lg * 8);
      c = MFMA(a, bq[kk], c, 0, 0, 0);
    }
    u2v pk;
    pk[0] = pack_bf(c[0], c[1]);
    pk[1] = pack_bf(c[2], c[3]);
    *(u2v*)(lhb + qloc * 68 + ct * 16 + lg * 4) = pk;
  }
  float lwreg[2][4];
#pragma unroll
  for (int c1 = 0; c1 < 2; ++c1)
#pragma unroll
    for (int r = 0; r < 4; ++r)
      lwreg[c1][r] = bf2f(lhb[qloc * 68 + (c1 * 16 + lg * 4 + r) - y + 31]);
#pragma unroll
  for (int ct = 0; ct < 4; ++ct) {
    f4v c = {0.f, 0.f, 0.f, 0.f};
#pragma unroll
    for (int kk = 0; kk < 2; ++kk) {
      s8v a = *(const s8v*)(relb + (ct * 16 + l15) * 64 + kk * 32 + lg * 8);
      c = MFMA(a, bq[kk], c, 0, 0, 0);
    }
    u2v pk;
    pk[0] = pack_bf(c[0], c[1]);
    pk[1] = pack_bf(c[2], c[3]);
    *(u2v*)(lhb + qloc * 68 + ct * 16 + lg * 4) = pk;
  }

  float lsum = 0.f;
  f4v ao[4] = {};
  unsigned short* pw = PwB + w * 1152;

  auto tile = [&](const unsigned short* Kc, const unsigned short* Vc, int n0) {
    int ib = qloc * 68 + (n0 >> 5) - x + 31;
    float lh0 = bf2f(lhb[ib]);
    float lh1 = bf2f(lhb[ib + 1]);
#pragma unroll
    for (int ct = 0; ct < 4; ++ct) {
      float lh = (ct & 2) ? lh1 : lh0;
      f4v c;
#pragma unroll
      for (int r = 0; r < 4; ++r) c[r] = lh + lwreg[ct & 1][r];
#pragma unroll
      for (int kk = 0; kk < 2; ++kk)
        c = MFMA(frag64(Kc, ct * 16 + l15, kk * 4 + lg), bq[kk], c, 0, 0, 0);
      f4v e;
#pragma unroll
      for (int r = 0; r < 4; ++r) e[r] = __builtin_amdgcn_exp2f(c[r]);
      lsum += (e[0] + e[1]) + (e[2] + e[3]);
      u2v pk;
      pk[0] = pack_bf(e[0], e[1]);
      pk[1] = pack_bf(e[2], e[3]);
      *(u2v*)(pw + l15 * 72 + ct * 16 + lg * 4) = pk;
    }
    s8v ap[2];
#pragma unroll
    for (int kk = 0; kk < 2; ++kk)
      ap[kk] = *(const s8v*)(pw + l15 * 72 + kk * 32 + lg * 8);
    // O^T = mfma(Vt, P): D[row=(lg,r) <-> d][col=l15 <-> q]
#pragma unroll
    for (int dt = 0; dt < 4; ++dt)
#pragma unroll
      for (int kk = 0; kk < 2; ++kk)
        ao[dt] = MFMA(frag64(Vc, dt * 16 + l15, kk * 4 + lg), ap[kk], ao[dt], 0, 0, 0);
  };

  __syncthreads();                       // tile 0 staged
  for (int t = 0; t < 16; t += 2) {
    // prefetch t+1 into buf1, compute t from buf0
    stage64(K1, kh + (t + 1) * 4096, 64, tid);
    stage64(V1, vh + (t + 1) * 64, 1024, tid);
    tile(K0, V0, t * 64);
    __syncthreads();
    // prefetch t+2 into buf0, compute t+1 from buf1
    if (t < 14) {
      stage64(K0, kh + (t + 2) * 4096, 64, tid);
      stage64(V0, vh + (t + 2) * 64, 1024, tid);
    }
    tile(K1, V1, (t + 1) * 64);
    __syncthreads();
  }

  lsum += __shfl_xor(lsum, 16);
  lsum += __shfl_xor(lsum, 32);
  float inv = 1.0f / lsum;
  // AO [b][h][q][64]
#pragma unroll
  for (int dt = 0; dt < 4; ++dt) {
    u2v pk;
    pk[0] = pack_bf(ao[dt][0] * inv, ao[dt][1] * inv);
    pk[1] = pack_bf(ao[dt][2] * inv, ao[dt][3] * inv);
    *(u2v*)(AO + (bh * 1024 + qrow) * 64 + dt * 16 + lg * 4) = pk;
  }
}

// ---------------- output projection, 128x128 tile, XCD-swizzled ----------------
__global__ __launch_bounds__(256, 2)
void out_gemm(const unsigned short* __restrict__ Wo,
              const unsigned short* __restrict__ AO,
              const float* __restrict__ bo,
              float* __restrict__ out) {
  __shared__ __align__(16) unsigned short Al[8192];
  __shared__ __align__(16) unsigned short Bl[8192];
  const int tid = threadIdx.x, w = tid >> 6, l = tid & 63;
  const int l15 = l & 15, lg = l >> 4;
  const int wr = w >> 1, wc = w & 1;
  const int bid = blockIdx.x;
  const int cls = bid & 7, idx = bid >> 3;     // 512 blocks
  const int n0 = cls * 128;
  const int m0 = (idx & 3) * 128;
  const int b  = idx >> 2;
  f4v acc[4][4] = {};
  for (int k0 = 0; k0 < 512; k0 += 64) {
    stage128(Al, Wo + m0 * 512 + k0, 512, tid);
    stage128(Bl, AO + ((b * 8 + (k0 >> 6)) * 1024 + n0) * 64, 64, tid);
    __syncthreads();
#pragma unroll
    for (int kk = 0; kk < 2; ++kk) {
      s8v a[4], bb[4];
#pragma unroll
      for (int i = 0; i < 4; ++i) a[i] = frag64(Al + wr * 4096, i * 16 + l15, kk * 4 + lg);
#pragma unroll
      for (int j = 0; j < 4; ++j) bb[j] = frag64(Bl + wc * 4096, j * 16 + l15, kk * 4 + lg);
#pragma unroll
      for (int i = 0; i < 4; ++i)
#pragma unroll
        for (int j = 0; j < 4; ++j)
          acc[i][j] = MFMA(a[i], bb[j], acc[i][j], 0, 0, 0);
    }
    __syncthreads();
  }
#pragma unroll
  for (int i = 0; i < 4; ++i) {
    int ob = m0 + wr * 64 + i * 16 + lg * 4;
    float b0 = bo[ob], b1 = bo[ob + 1], b2 = bo[ob + 2], b3 = bo[ob + 3];
#pragma unroll
    for (int j = 0; j < 4; ++j) {
      int n = n0 + wc * 64 + j * 16 + l15;
      float* op = out + (b * 512 + ob) * 1024 + n;
      op[0]    = acc[i][j][0] + b0;
      op[1024] = acc[i][j][1] + b1;
      op[2048] = acc[i][j][2] + b2;
      op[3072] = acc[i][j][3] + b3;
    }
  }
}

// ---------------- launch ----------------

extern "C" void kernel_launch(void* const* d_in, const int* in_sizes, int n_in,
                              void* d_out, int out_size, void* d_ws, size_t ws_size,
                              hipStream_t stream) {
  const float* x    = (const float*)d_in[0];
  const float* wq   = (const float*)d_in[1];
  const float* wk   = (const float*)d_in[2];
  const float* wv   = (const float*)d_in[3];
  const float* wo   = (const float*)d_in[4];
  const float* bo   = (const float*)d_in[5];
  const float* relh = (const float*)d_in[6];
  const float* relw = (const float*)d_in[7];
  char* ws = (char*)d_ws;
  unsigned short* Xt   = (unsigned short*)(ws + 0);         // 16 MiB (reused as AO)
  unsigned short* AO   = (unsigned short*)(ws + 0);
  unsigned short* Wqkv = (unsigned short*)(ws + 16777216);  // 1.5 MiB
  unsigned short* Wob  = (unsigned short*)(ws + 18350080);  // 0.5 MiB
  unsigned short* Rel  = (unsigned short*)(ws + 18874368);  // 16 KiB
  unsigned short* Qb   = (unsigned short*)(ws + 18890752);  // 16 MiB
  unsigned short* Kb   = (unsigned short*)(ws + 35667968);  // 16 MiB
  unsigned short* Vt   = (unsigned short*)(ws + 52445184);  // 16 MiB
  float* out = (float*)d_out;

  cvt_all<<<1056, 256, 0, stream>>>(wq, wk, wv, wo, relh, relw, Wqkv, Wob, Rel);
  xpose<<<dim3(16, 32, 16), 256, 0, stream>>>(x, Xt);
  qkv_gemm<<<1536, 256, 0, stream>>>(Wqkv, Xt, Qb, Kb, Vt);
  attn_kernel<<<2048, 256, 0, stream>>>(Qb, Kb, Vt, Rel, AO);
  out_gemm<<<512, 256, 0, stream>>>(Wob, AO, bo, out);
}

// Round 9
// 202.463 us; speedup vs baseline: 1.1404x; 1.1404x over previous
//
#include <hip/hip_runtime.h>

typedef __attribute__((ext_vector_type(8))) short s8v;          // 8 x bf16 (raw)
typedef __attribute__((ext_vector_type(4))) float f4v;
typedef __attribute__((ext_vector_type(4))) unsigned short u4v;
typedef __attribute__((ext_vector_type(2))) unsigned int u2v;
typedef __attribute__((ext_vector_type(4))) float fl4;

#define MFMA __builtin_amdgcn_mfma_f32_16x16x32_bf16
#define LOG2E 1.44269504088896340736f
#define QSCALE (0.125f * LOG2E)   // fold 1/sqrt(DK) and log2(e) into q

// round-half-up bf16 (0.5 ulp, fine for our budget)
__device__ __forceinline__ unsigned short f2bf(float f) {
  return (unsigned short)((__float_as_uint(f) + 0x8000u) >> 16);
}
// pack two floats -> two bf16 in one dword (low = a, high = b)
__device__ __forceinline__ unsigned int pack_bf(float a, float b) {
  return __builtin_amdgcn_perm(__float_as_uint(b) + 0x8000u,
                               __float_as_uint(a) + 0x8000u, 0x07060302u);
}
__device__ __forceinline__ float bf2f(unsigned short u) {
  return __uint_as_float(((unsigned int)u) << 16);
}

__device__ __forceinline__ void gload16(const void* g, void* l) {
  __builtin_amdgcn_global_load_lds(
      (const __attribute__((address_space(1))) unsigned int*)g,
      (__attribute__((address_space(3))) unsigned int*)l,
      16, 0, 0);
}

// ---- 64x64 bf16 tile staging, XOR-chunk swizzle (LDS chunk (row,cl) holds
// global chunk (row, cl^(row&7))); frag64 applies the same XOR on read.
// 4-wave variant (2 gloads/wave):
__device__ __forceinline__ void stage64(unsigned short* lds,
                                        const unsigned short* src,
                                        int src_ld, int tid) {
  const int w = tid >> 6, l = tid & 63;
#pragma unroll
  for (int c = 0; c < 2; ++c) {
    int idx = (c * 4 + w) * 64 + l;
    int row = idx >> 3, cl = idx & 7;
    gload16(src + row * src_ld + ((cl ^ (row & 7)) << 3),
            lds + (c * 4 + w) * 512);
  }
}
// 8-wave variant (1 gload/wave): thread (w,l) stages chunk w*64+l
__device__ __forceinline__ void stage64_8w(unsigned short* lds,
                                           const unsigned short* src,
                                           int src_ld, int w, int l) {
  int row = w * 8 + (l >> 3), cl = l & 7;
  gload16(src + row * src_ld + ((cl ^ (row & 7)) << 3),
          lds + w * 512);
}
// ---- 128x64 bf16 tile staging (for 128^2 GEMM)
__device__ __forceinline__ void stage128(unsigned short* lds,
                                         const unsigned short* src,
                                         int src_ld, int tid) {
  const int w = tid >> 6, l = tid & 63;
#pragma unroll
  for (int c = 0; c < 4; ++c) {
    int id = c * 256 + w * 64 + l;
    int row = id >> 3, cl = id & 7;
    gload16(src + row * src_ld + ((cl ^ (row & 7)) << 3),
            lds + (c * 256 + w * 64) * 8);
  }
}
__device__ __forceinline__ s8v frag64(const unsigned short* lds, int row, int chunk) {
  return *(const s8v*)(lds + row * 64 + ((chunk ^ (row & 7)) << 3));
}

// ---------------- converts (merged: wqkv rows 0..767, wo 768..1023, rel 1024..1055) ----
__global__ void cvt_all(const float* __restrict__ wq, const float* __restrict__ wk,
                        const float* __restrict__ wv, const float* __restrict__ wo,
                        const float* __restrict__ relh, const float* __restrict__ relw,
                        unsigned short* __restrict__ Wqkv, unsigned short* __restrict__ Wob,
                        unsigned short* __restrict__ Rel) {
  const int bid = blockIdx.x, tid = threadIdx.x;
  if (bid < 768) {
    int i = bid * 256 + tid;                       // 1536*128
    int orow = i >> 7, c4 = (i & 127) * 4;
    int p = orow >> 9, oc = orow & 511;
    int h = oc >> 6, d = oc & 63;
    const float* w = (p == 0) ? wq : (p == 1) ? wk : wv;
    fl4 v = *(const fl4*)(w + (d * 8 + h) * 512 + c4);
    u4v o;
    o[0] = f2bf(v[0]); o[1] = f2bf(v[1]); o[2] = f2bf(v[2]); o[3] = f2bf(v[3]);
    *(u4v*)(Wqkv + orow * 512 + c4) = o;
  } else if (bid < 1024) {
    int i = (bid - 768) * 256 + tid;               // 65536 float4s
    fl4 v = ((const fl4*)wo)[i];
    u4v o;
    o[0] = f2bf(v[0]); o[1] = f2bf(v[1]); o[2] = f2bf(v[2]); o[3] = f2bf(v[3]);
    ((u4v*)Wob)[i] = o;
  } else {
    int i = (bid - 1024) * 256 + tid;              // [2][64][64], row 63 zeroed
    int t = i >> 12, r = (i >> 6) & 63, d = i & 63;
    const float* s = t ? relw : relh;
    Rel[i] = (r < 63) ? f2bf(s[r * 64 + d]) : (unsigned short)0;
  }
}

// x [B][C][N] f32 -> Xt [B][N][C] bf16
__global__ void xpose(const float* __restrict__ x, unsigned short* __restrict__ Xt) {
  __shared__ float tls[32][33];
  const int c0 = blockIdx.x * 32, n0 = blockIdx.y * 32, b = blockIdx.z;
  const int tid = threadIdx.x;
  const int rr = tid >> 3, cc4 = (tid & 7) * 4;
  fl4 v = *(const fl4*)(x + (b * 512 + c0 + rr) * 1024 + n0 + cc4);
#pragma unroll
  for (int i = 0; i < 4; ++i) tls[rr][cc4 + i] = v[i];
  __syncthreads();
  u4v o;
#pragma unroll
  for (int i = 0; i < 4; ++i) o[i] = f2bf(tls[cc4 + i][rr]);
  *(u4v*)(Xt + (b * 1024 + n0 + rr) * 512 + c0 + cc4) = o;
}

// ---------------- QKV projection, 128x128 tile ----------------
// 1-D grid, XCD-swizzled: cls=bid%8 keys the (n,b) B-panel class (n_idx=cls);
// within an XCD, same-(n,b) panels are consecutive across m (12x L2 reuse).
__global__ __launch_bounds__(256, 2)
void qkv_gemm(const unsigned short* __restrict__ W,
              const unsigned short* __restrict__ Xt,
              unsigned short* __restrict__ qb,
              unsigned short* __restrict__ kb,
              unsigned short* __restrict__ vtb) {
  __shared__ __align__(16) unsigned short Al[8192];
  __shared__ __align__(16) unsigned short Bl[8192];
  const int tid = threadIdx.x, w = tid >> 6, l = tid & 63;
  const int l15 = l & 15, lg = l >> 4;
  const int wr = w >> 1, wc = w & 1;
  const int bid = blockIdx.x;
  const int cls = bid & 7, idx = bid >> 3;     // 1536 blocks: cls=XCD class
  const int n0 = cls * 128;
  const int m0 = (idx % 12) * 128;
  const int b  = idx / 12;
  f4v acc[4][4] = {};
  const unsigned short* As = W + m0 * 512;
  const unsigned short* Bs = Xt + (b * 1024 + n0) * 512;
  for (int k0 = 0; k0 < 512; k0 += 64) {
    stage128(Al, As + k0, 512, tid);
    stage128(Bl, Bs + k0, 512, tid);
    __syncthreads();
#pragma unroll
    for (int kk = 0; kk < 2; ++kk) {
      s8v a[4], bb[4];
#pragma unroll
      for (int i = 0; i < 4; ++i) a[i] = frag64(Al + wr * 4096, i * 16 + l15, kk * 4 + lg);
#pragma unroll
      for (int j = 0; j < 4; ++j) bb[j] = frag64(Bl + wc * 4096, j * 16 + l15, kk * 4 + lg);
#pragma unroll
      for (int i = 0; i < 4; ++i)
#pragma unroll
        for (int j = 0; j < 4; ++j)
          acc[i][j] = MFMA(a[i], bb[j], acc[i][j], 0, 0, 0);
    }
    __syncthreads();
  }
  const int p = m0 >> 9;
  const float sc = (p == 0) ? QSCALE : 1.0f;
#pragma unroll
  for (int i = 0; i < 4; ++i) {
    int o = m0 + wr * 64 + i * 16 + lg * 4;
    int oc = o & 511, hh = oc >> 6, dd = oc & 63;
#pragma unroll
    for (int j = 0; j < 4; ++j) {
      int n = n0 + wc * 64 + j * 16 + l15;
      if (p < 2) {
        u2v pk;
        pk[0] = pack_bf(acc[i][j][0] * sc, acc[i][j][1] * sc);
        pk[1] = pack_bf(acc[i][j][2] * sc, acc[i][j][3] * sc);
        unsigned short* dst = (p == 0 ? qb : kb) + (((b * 8 + hh) * 1024 + n) * 64 + dd);
        *(u2v*)dst = pk;
      } else {
#pragma unroll
        for (int r = 0; r < 4; ++r)
          vtb[((b * 8 + hh) * 64 + dd + r) * 1024 + n] = f2bf(acc[i][j][r]);
      }
    }
  }
}

// ---------------- fused attention: 8 waves, QBLK=128, dbuf prefetch, XCD swizzle ----
// 1-D grid 1024 x 512 threads: cls=bid%8 -> bh%8 (XCD class); 8 q-blocks of one
// head consecutive within class -> head's K/V L2-resident.
// K/V tile shared by 128 q-rows (2x round 8) -> half the staging per wave and
// 2 blocks/CU x 8 waves = 16 waves/CU (50% occupancy ceiling vs 37.5%).
__global__ __launch_bounds__(512, 4)
void attn_kernel(const unsigned short* __restrict__ qbuf,
                 const unsigned short* __restrict__ kbuf,
                 const unsigned short* __restrict__ vtbuf,
                 const unsigned short* __restrict__ relb,
                 unsigned short* __restrict__ AO) {
  __shared__ __align__(16) unsigned short SH[34304];
  unsigned short* K0  = SH;            // [64][64] xor-chunked (4096 el each)
  unsigned short* V0  = SH + 4096;
  unsigned short* K1  = SH + 8192;
  unsigned short* V1  = SH + 12288;
  unsigned short* lhb = SH + 16384;    // [128][68] bf16 (lw scratch then lh; rows lane-private)
  unsigned short* PwB = SH + 25088;    // 8 x [16][72] bf16

  const int tid = threadIdx.x, w = tid >> 6, l = tid & 63;
  const int l15 = l & 15, lg = l >> 4;
  const int bid = blockIdx.x;
  const int cls = bid & 7, idx = bid >> 3;
  const int q0 = (idx & 7) * 128;
  const int bh = cls + 8 * (idx >> 3);
  const unsigned short* qh = qbuf + bh * 65536;
  const unsigned short* kh = kbuf + bh * 65536;
  const unsigned short* vh = vtbuf + bh * 65536;
  const int qloc = w * 16 + l15;       // [0,128)
  const int qrow = q0 + qloc;
  const int x = qrow >> 5, y = qrow & 31;

  // issue tile-0 staging first; table work below hides its latency
  stage64_8w(K0, kh, 64, w, l);
  stage64_8w(V0, vh, 1024, w, l);

  // Q B-frags (own q row over d), q pre-scaled by log2e/8
  s8v bq[2];
#pragma unroll
  for (int kk = 0; kk < 2; ++kk)
    bq[kk] = *(const s8v*)(qh + qrow * 64 + kk * 32 + lg * 8);

  // lw table first (into lhb), read lw regs, then lh table (overwrites).
  // All rows lane-private within a wave -> DS in-order, no barriers needed.
#pragma unroll
  for (int ct = 0; ct < 4; ++ct) {
    f4v c = {0.f, 0.f, 0.f, 0.f};
#pragma unroll
    for (int kk = 0; kk < 2; ++kk) {
      s8v a = *(const s8v*)(relb + 4096 + (ct * 16 + l15) * 64 + kk * 32 + lg * 8);
      c = MFMA(a, bq[kk], c, 0, 0, 0);
    }
    u2v pk;
    pk[0] = pack_bf(c[0], c[1]);
    pk[1] = pack_bf(c[2], c[3]);
    *(u2v*)(lhb + qloc * 68 + ct * 16 + lg * 4) = pk;
  }
  float lwreg[2][4];
#pragma unroll
  for (int c1 = 0; c1 < 2; ++c1)
#pragma unroll
    for (int r = 0; r < 4; ++r)
      lwreg[c1][r] = bf2f(lhb[qloc * 68 + (c1 * 16 + lg * 4 + r) - y + 31]);
#pragma unroll
  for (int ct = 0; ct < 4; ++ct) {
    f4v c = {0.f, 0.f, 0.f, 0.f};
#pragma unroll
    for (int kk = 0; kk < 2; ++kk) {
      s8v a = *(const s8v*)(relb + (ct * 16 + l15) * 64 + kk * 32 + lg * 8);
      c = MFMA(a, bq[kk], c, 0, 0, 0);
    }
    u2v pk;
    pk[0] = pack_bf(c[0], c[1]);
    pk[1] = pack_bf(c[2], c[3]);
    *(u2v*)(lhb + qloc * 68 + ct * 16 + lg * 4) = pk;
  }

  float lsum = 0.f;
  f4v ao[4] = {};
  unsigned short* pw = PwB + w * 1152;

  auto tile = [&](const unsigned short* Kc, const unsigned short* Vc, int n0) {
    int ib = qloc * 68 + (n0 >> 5) - x + 31;
    float lh0 = bf2f(lhb[ib]);
    float lh1 = bf2f(lhb[ib + 1]);
#pragma unroll
    for (int ct = 0; ct < 4; ++ct) {
      float lh = (ct & 2) ? lh1 : lh0;
      f4v c;
#pragma unroll
      for (int r = 0; r < 4; ++r) c[r] = lh + lwreg[ct & 1][r];
#pragma unroll
      for (int kk = 0; kk < 2; ++kk)
        c = MFMA(frag64(Kc, ct * 16 + l15, kk * 4 + lg), bq[kk], c, 0, 0, 0);
      f4v e;
#pragma unroll
      for (int r = 0; r < 4; ++r) e[r] = __builtin_amdgcn_exp2f(c[r]);
      lsum += (e[0] + e[1]) + (e[2] + e[3]);
      u2v pk;
      pk[0] = pack_bf(e[0], e[1]);
      pk[1] = pack_bf(e[2], e[3]);
      *(u2v*)(pw + l15 * 72 + ct * 16 + lg * 4) = pk;
    }
    s8v ap[2];
#pragma unroll
    for (int kk = 0; kk < 2; ++kk)
      ap[kk] = *(const s8v*)(pw + l15 * 72 + kk * 32 + lg * 8);
    // O^T = mfma(Vt, P): D[row=(lg,r) <-> d][col=l15 <-> q]
#pragma unroll
    for (int dt = 0; dt < 4; ++dt)
#pragma unroll
      for (int kk = 0; kk < 2; ++kk)
        ao[dt] = MFMA(frag64(Vc, dt * 16 + l15, kk * 4 + lg), ap[kk], ao[dt], 0, 0, 0);
  };

  __syncthreads();                       // tile 0 staged
  for (int t = 0; t < 16; t += 2) {
    // prefetch t+1 into buf1, compute t from buf0
    stage64_8w(K1, kh + (t + 1) * 4096, 64, w, l);
    stage64_8w(V1, vh + (t + 1) * 64, 1024, w, l);
    tile(K0, V0, t * 64);
    __syncthreads();
    // prefetch t+2 into buf0, compute t+1 from buf1
    if (t < 14) {
      stage64_8w(K0, kh + (t + 2) * 4096, 64, w, l);
      stage64_8w(V0, vh + (t + 2) * 64, 1024, w, l);
    }
    tile(K1, V1, (t + 1) * 64);
    __syncthreads();
  }

  lsum += __shfl_xor(lsum, 16);
  lsum += __shfl_xor(lsum, 32);
  float inv = 1.0f / lsum;
  // AO [b][h][q][64]
#pragma unroll
  for (int dt = 0; dt < 4; ++dt) {
    u2v pk;
    pk[0] = pack_bf(ao[dt][0] * inv, ao[dt][1] * inv);
    pk[1] = pack_bf(ao[dt][2] * inv, ao[dt][3] * inv);
    *(u2v*)(AO + (bh * 1024 + qrow) * 64 + dt * 16 + lg * 4) = pk;
  }
}

// ---------------- output projection, 128x128 tile, XCD-swizzled ----------------
__global__ __launch_bounds__(256, 2)
void out_gemm(const unsigned short* __restrict__ Wo,
              const unsigned short* __restrict__ AO,
              const float* __restrict__ bo,
              float* __restrict__ out) {
  __shared__ __align__(16) unsigned short Al[8192];
  __shared__ __align__(16) unsigned short Bl[8192];
  const int tid = threadIdx.x, w = tid >> 6, l = tid & 63;
  const int l15 = l & 15, lg = l >> 4;
  const int wr = w >> 1, wc = w & 1;
  const int bid = blockIdx.x;
  const int cls = bid & 7, idx = bid >> 3;     // 512 blocks
  const int n0 = cls * 128;
  const int m0 = (idx & 3) * 128;
  const int b  = idx >> 2;
  f4v acc[4][4] = {};
  for (int k0 = 0; k0 < 512; k0 += 64) {
    stage128(Al, Wo + m0 * 512 + k0, 512, tid);
    stage128(Bl, AO + ((b * 8 + (k0 >> 6)) * 1024 + n0) * 64, 64, tid);
    __syncthreads();
#pragma unroll
    for (int kk = 0; kk < 2; ++kk) {
      s8v a[4], bb[4];
#pragma unroll
      for (int i = 0; i < 4; ++i) a[i] = frag64(Al + wr * 4096, i * 16 + l15, kk * 4 + lg);
#pragma unroll
      for (int j = 0; j < 4; ++j) bb[j] = frag64(Bl + wc * 4096, j * 16 + l15, kk * 4 + lg);
#pragma unroll
      for (int i = 0; i < 4; ++i)
#pragma unroll
        for (int j = 0; j < 4; ++j)
          acc[i][j] = MFMA(a[i], bb[j], acc[i][j], 0, 0, 0);
    }
    __syncthreads();
  }
#pragma unroll
  for (int i = 0; i < 4; ++i) {
    int ob = m0 + wr * 64 + i * 16 + lg * 4;
    float b0 = bo[ob], b1 = bo[ob + 1], b2 = bo[ob + 2], b3 = bo[ob + 3];
#pragma unroll
    for (int j = 0; j < 4; ++j) {
      int n = n0 + wc * 64 + j * 16 + l15;
      float* op = out + (b * 512 + ob) * 1024 + n;
      op[0]    = acc[i][j][0] + b0;
      op[1024] = acc[i][j][1] + b1;
      op[2048] = acc[i][j][2] + b2;
      op[3072] = acc[i][j][3] + b3;
    }
  }
}

// ---------------- launch ----------------

extern "C" void kernel_launch(void* const* d_in, const int* in_sizes, int n_in,
                              void* d_out, int out_size, void* d_ws, size_t ws_size,
                              hipStream_t stream) {
  const float* x    = (const float*)d_in[0];
  const float* wq   = (const float*)d_in[1];
  const float* wk   = (const float*)d_in[2];
  const float* wv   = (const float*)d_in[3];
  const float* wo   = (const float*)d_in[4];
  const float* bo   = (const float*)d_in[5];
  const float* relh = (const float*)d_in[6];
  const float* relw = (const float*)d_in[7];
  char* ws = (char*)d_ws;
  unsigned short* Xt   = (unsigned short*)(ws + 0);         // 16 MiB (reused as AO)
  unsigned short* AO   = (unsigned short*)(ws + 0);
  unsigned short* Wqkv = (unsigned short*)(ws + 16777216);  // 1.5 MiB
  unsigned short* Wob  = (unsigned short*)(ws + 18350080);  // 0.5 MiB
  unsigned short* Rel  = (unsigned short*)(ws + 18874368);  // 16 KiB
  unsigned short* Qb   = (unsigned short*)(ws + 18890752);  // 16 MiB
  unsigned short* Kb   = (unsigned short*)(ws + 35667968);  // 16 MiB
  unsigned short* Vt   = (unsigned short*)(ws + 52445184);  // 16 MiB
  float* out = (float*)d_out;

  cvt_all<<<1056, 256, 0, stream>>>(wq, wk, wv, wo, relh, relw, Wqkv, Wob, Rel);
  xpose<<<dim3(16, 32, 16), 256, 0, stream>>>(x, Xt);
  qkv_gemm<<<1536, 256, 0, stream>>>(Wqkv, Xt, Qb, Kb, Vt);
  attn_kernel<<<1024, 512, 0, stream>>>(Qb, Kb, Vt, Rel, AO);
  out_gemm<<<512, 256, 0, stream>>>(Wob, AO, bo, out);
}